// Round 3
// baseline (4431.721 us; speedup 1.0000x reference)
//
#include <hip/hip_runtime.h>
#include <hip/hip_bf16.h>
#include <stdint.h>

#define SEQ   512
#define BATCH 1024
#define IN_F  256
#define HID   512
#define OUT_F 64

// ws layout (bytes)
static const size_t OFF_V   = 0;          // 1024*512*4 = 2 MB   [b*512 + 64q + lane]
static const size_t OFF_I   = 2097152;    // 2 MB
static const size_t OFF_VO  = 4194304;    // 256 KB
static const size_t OFF_IO  = 4456448;    // 256 KB
static const size_t OFF_ZM  = 4718592;    // 1024*8*8 = 64 KB
static const size_t OFF_WRT = 4784128;    // 513*512*4 (row 512 zeros, unused pad)
static const size_t OFF_WOT = 5834752;    // 513*64*4 = 131328 (fp32)
static const size_t OFF_CUR = 5966080;    // csteps*1024*512*4

__global__ void init_state_kernel(float4* __restrict__ p, int n4) {
    int i = blockIdx.x * blockDim.x + threadIdx.x;
    int stride = gridDim.x * blockDim.x;
    float4 z = make_float4(0.f, 0.f, 0.f, 0.f);
    for (; i < n4; i += stride) p[i] = z;
}

__global__ void prep_kernel(const float* __restrict__ wrec, const float* __restrict__ wout,
                            float* __restrict__ wrecT, float* __restrict__ woutT) {
    int i = blockIdx.x * blockDim.x + threadIdx.x;
    int stride = gridDim.x * blockDim.x;
    for (int idx = i; idx < 513 * 512; idx += stride) {
        int j = idx >> 9, h = idx & 511;
        wrecT[idx] = (j < 512) ? wrec[h * 512 + j] : 0.0f;   // wrecT[j][h] = w_rec[h][j]
    }
    for (int idx = i; idx < 513 * 64; idx += stride) {
        int h = idx >> 6, o = idx & 63;
        woutT[idx] = (h < 512) ? wout[o * 512 + h] : 0.0f;   // woutT[h][o] = w_out[o][h]
    }
}

// ===== VERBATIM R1 GEMM (fp32 VALU) — bit-identical cur =====
// C[m][n] = sum_k A[m][k] * B[n][k];  A:[Mc][256] B:[512][256] C:[Mc][512]
__launch_bounds__(256)
__global__ void gemm_kernel(const float* __restrict__ A, const float* __restrict__ Bw,
                            float* __restrict__ C) {
    __shared__ float As[16 * 64];
    __shared__ float Bs[16 * 64];
    const int t = threadIdx.x;
    const size_t m0 = (size_t)blockIdx.x * 64;
    const int n0 = blockIdx.y * 64;
    const int tn = t & 15, tm = t >> 4;      // 16x16 thread grid, 4x4 microtile
    const int lm = t >> 2, lk = (t & 3) << 2;
    const float* Ap = A + (m0 + (size_t)lm) * IN_F + lk;
    const float* Bp = Bw + (size_t)(n0 + lm) * IN_F + lk;
    float acc[4][4] = {{0.f}};
    for (int k0 = 0; k0 < IN_F; k0 += 16) {
        float4 a4 = *(const float4*)(Ap + k0);
        float4 b4 = *(const float4*)(Bp + k0);
        __syncthreads();
        As[(lk + 0) * 64 + lm] = a4.x;
        As[(lk + 1) * 64 + lm] = a4.y;
        As[(lk + 2) * 64 + lm] = a4.z;
        As[(lk + 3) * 64 + lm] = a4.w;
        Bs[(lk + 0) * 64 + lm] = b4.x;
        Bs[(lk + 1) * 64 + lm] = b4.y;
        Bs[(lk + 2) * 64 + lm] = b4.z;
        Bs[(lk + 3) * 64 + lm] = b4.w;
        __syncthreads();
        #pragma unroll
        for (int k = 0; k < 16; ++k) {
            float4 av = *(const float4*)&As[k * 64 + 4 * tm];
            float4 bv = *(const float4*)&Bs[k * 64 + 4 * tn];
            acc[0][0] += av.x * bv.x; acc[0][1] += av.x * bv.y; acc[0][2] += av.x * bv.z; acc[0][3] += av.x * bv.w;
            acc[1][0] += av.y * bv.x; acc[1][1] += av.y * bv.y; acc[1][2] += av.y * bv.z; acc[1][3] += av.y * bv.w;
            acc[2][0] += av.z * bv.x; acc[2][1] += av.z * bv.y; acc[2][2] += av.z * bv.z; acc[2][3] += av.z * bv.w;
            acc[3][0] += av.w * bv.x; acc[3][1] += av.w * bv.y; acc[3][2] += av.w * bv.z; acc[3][3] += av.w * bv.w;
        }
    }
    float* Cp = C + (m0 + (size_t)(4 * tm)) * HID + n0 + 4 * tn;
    #pragma unroll
    for (int r = 0; r < 4; ++r) {
        float4 cv = make_float4(acc[r][0], acc[r][1], acc[r][2], acc[r][3]);
        *(float4*)(Cp + (size_t)r * HID) = cv;
    }
}

// ===== Wave-per-batch recurrent kernel: zero barriers, zero LDS =====
// Block = 256 threads = 4 waves; wave wv handles batch b = blockIdx.x*4 + wv.
// Lane owns hidden units h = 64q + lane, q = 0..7. Spike exchange via __ballot.
// Gather order ascending j (q-major, ctz-minor) == R1's slist order -> the
// closed-loop (v, i, z) arithmetic is bit-identical to the R1 passing run.
__launch_bounds__(256)
__global__ void rec_kernel(const float* __restrict__ cur,
                           const float* __restrict__ wrecT,
                           const float* __restrict__ woutT,
                           float* __restrict__ stV, float* __restrict__ stI,
                           float* __restrict__ stVO, float* __restrict__ stIO,
                           unsigned long long* __restrict__ stZM,
                           float* __restrict__ out, int t0, int csteps) {
    const int lane = threadIdx.x & 63;
    const int wv = threadIdx.x >> 6;
    const int b = blockIdx.x * 4 + wv;

    float v[8], ci[8];
    unsigned long long mask[8];
    #pragma unroll
    for (int q = 0; q < 8; ++q) {
        v[q]  = stV[b * HID + q * 64 + lane];
        ci[q] = stI[b * HID + q * 64 + lane];
    }
    float vo = stVO[b * OUT_F + lane];
    float io = stIO[b * OUT_F + lane];
    #pragma unroll
    for (int q = 0; q < 8; ++q) mask[q] = stZM[b * 8 + q];

    const size_t step_stride = (size_t)BATCH * HID;
    const float* curp = cur + (size_t)b * HID + lane;
    float curv[8], curn[8];
    #pragma unroll
    for (int q = 0; q < 8; ++q) curv[q] = curp[q * 64];

    for (int tl = 0; tl < csteps; ++tl) {
        // prefetch next step's input current (overlaps with the gather)
        if (tl + 1 < csteps) {
            const float* np = curp + (size_t)(tl + 1) * step_stride;
            #pragma unroll
            for (int q = 0; q < 8; ++q) curn[q] = np[q * 64];
        }

        // recurrent input: sum w_rec columns of last step's spikes, ascending j
        float rec[8] = {0.f, 0.f, 0.f, 0.f, 0.f, 0.f, 0.f, 0.f};
        #pragma unroll
        for (int q = 0; q < 8; ++q) {
            unsigned long long mm = mask[q];
            while (mm) {
                int j = __builtin_ctzll(mm);
                mm &= mm - 1;
                const float* wr = wrecT + ((size_t)(q * 64 + j)) * HID + lane;
                #pragma unroll
                for (int p = 0; p < 8; ++p) rec[p] += wr[p * 64];
            }
        }

        // LIF update (expression forms mirror the reference)
        unsigned long long nm[8];
        #pragma unroll
        for (int q = 0; q < 8; ++q) {
            float vdec = v[q] + 0.1f * ((0.0f - v[q]) + ci[q]);
            int spk = vdec > 1.0f;
            v[q] = spk ? 0.0f : vdec;
            float idec = ci[q] + 0.2f * (0.0f - ci[q]);
            ci[q] = (idec + curv[q]) + rec[q];
            nm[q] = __ballot(spk);
            mask[q] = nm[q];
        }

        // readout y = z_new @ w_out^T (open loop, fp32), lane = output feature
        float y = 0.f;
        #pragma unroll
        for (int q = 0; q < 8; ++q) {
            unsigned long long mm = nm[q];
            while (mm) {
                int j = __builtin_ctzll(mm);
                mm &= mm - 1;
                y += woutT[((size_t)(q * 64 + j)) * OUT_F + lane];
            }
        }

        // LI readout cell
        float von = vo + 0.1f * ((0.0f - vo) + io);
        float iodec = io + 0.2f * (0.0f - io);
        io = iodec + y;
        vo = von;
        out[(((size_t)(t0 + tl)) * BATCH + b) * OUT_F + lane] = von;

        #pragma unroll
        for (int q = 0; q < 8; ++q) curv[q] = curn[q];
    }

    #pragma unroll
    for (int q = 0; q < 8; ++q) {
        stV[b * HID + q * 64 + lane] = v[q];
        stI[b * HID + q * 64 + lane] = ci[q];
    }
    stVO[b * OUT_F + lane] = vo;
    stIO[b * OUT_F + lane] = io;
    #pragma unroll
    for (int q = 0; q < 8; ++q)
        if (lane == q) stZM[b * 8 + q] = mask[q];   // static reg index (rule #20)
}

extern "C" void kernel_launch(void* const* d_in, const int* in_sizes, int n_in,
                              void* d_out, int out_size, void* d_ws, size_t ws_size,
                              hipStream_t stream) {
    const float* x     = (const float*)d_in[0];
    const float* w_in  = (const float*)d_in[1];
    const float* w_rec = (const float*)d_in[2];
    const float* w_out = (const float*)d_in[3];
    float* out = (float*)d_out;
    char* ws = (char*)d_ws;

    float* stV  = (float*)(ws + OFF_V);
    float* stI  = (float*)(ws + OFF_I);
    float* stVO = (float*)(ws + OFF_VO);
    float* stIO = (float*)(ws + OFF_IO);
    unsigned long long* stZM = (unsigned long long*)(ws + OFF_ZM);
    float* wrecT = (float*)(ws + OFF_WRT);
    float* woutT = (float*)(ws + OFF_WOT);
    float* curbuf = (float*)(ws + OFF_CUR);

    // largest power-of-2 step chunk whose cur buffer fits the scratch
    size_t cap = (ws_size > OFF_CUR) ? (ws_size - OFF_CUR) : 0;
    int csteps = 1;
    for (int c = 512; c >= 1; c >>= 1) {
        if ((size_t)c * (size_t)BATCH * HID * 4 <= cap) { csteps = c; break; }
    }

    {   // zero persistent state (v, i, vo, io, zmask)
        int n4 = (int)(OFF_WRT / 16);
        int blocks = (n4 + 255) / 256;
        if (blocks > 4096) blocks = 4096;
        hipLaunchKernelGGL(init_state_kernel, dim3(blocks), dim3(256), 0, stream,
                           (float4*)ws, n4);
    }
    hipLaunchKernelGGL(prep_kernel, dim3(512), dim3(256), 0, stream,
                       w_rec, w_out, wrecT, woutT);

    for (int t0 = 0; t0 < SEQ; t0 += csteps) {
        hipLaunchKernelGGL(gemm_kernel, dim3(csteps * (BATCH / 64), HID / 64), dim3(256), 0, stream,
                           x + (size_t)t0 * BATCH * IN_F, w_in, curbuf);
        hipLaunchKernelGGL(rec_kernel, dim3(BATCH / 4), dim3(256), 0, stream,
                           curbuf, wrecT, woutT, stV, stI, stVO, stIO, stZM, out, t0, csteps);
    }
}

// Round 5
// 3744.989 us; speedup vs baseline: 1.1834x; 1.1834x over previous
//
#include <hip/hip_runtime.h>
#include <hip/hip_bf16.h>
#include <stdint.h>

#define SEQ   512
#define BATCH 1024
#define IN_F  256
#define HID   512
#define OUT_F 64

// ws layout (bytes)
static const size_t OFF_V   = 0;          // 1024*512*4 = 2 MB
static const size_t OFF_I   = 2097152;    // 2 MB
static const size_t OFF_VO  = 4194304;    // 256 KB
static const size_t OFF_IO  = 4456448;    // 256 KB
static const size_t OFF_ZM  = 4718592;    // 64 KB
static const size_t OFF_WRT = 4784128;    // 513*512*4 (row 512 zeros)
static const size_t OFF_WOT = 5834752;    // 513*64*4 = 131328 (fp32, row 512 zeros)
static const size_t OFF_CUR = 5966080;    // csteps*1024*512*4

__global__ void init_state_kernel(float4* __restrict__ p, int n4) {
    int i = blockIdx.x * blockDim.x + threadIdx.x;
    int stride = gridDim.x * blockDim.x;
    float4 z = make_float4(0.f, 0.f, 0.f, 0.f);
    for (; i < n4; i += stride) p[i] = z;
}

__global__ void prep_kernel(const float* __restrict__ wrec, const float* __restrict__ wout,
                            float* __restrict__ wrecT, float* __restrict__ woutT) {
    int i = blockIdx.x * blockDim.x + threadIdx.x;
    int stride = gridDim.x * blockDim.x;
    for (int idx = i; idx < 513 * 512; idx += stride) {
        int j = idx >> 9, h = idx & 511;
        wrecT[idx] = (j < 512) ? wrec[h * 512 + j] : 0.0f;   // wrecT[j][h] = w_rec[h][j]
    }
    for (int idx = i; idx < 513 * 64; idx += stride) {
        int h = idx >> 6, o = idx & 63;
        woutT[idx] = (h < 512) ? wout[o * 512 + h] : 0.0f;   // woutT[h][o] = w_out[o][h]
    }
}

// ===== VERBATIM R1/R3 GEMM (fp32 VALU) — numerics LOCKED (bit-exact cur) =====
// C[m][n] = sum_k A[m][k] * B[n][k];  A:[Mc][256] B:[512][256] C:[Mc][512]
// Each output element accumulates k = 0..255 sequentially through one fmac
// chain — matches the reference's summation closely enough for ZERO spike
// flips (R1 absmax 0.0039, R3 absmax 0.0). Do NOT change the arithmetic.
__launch_bounds__(256)
__global__ void gemm_kernel(const float* __restrict__ A, const float* __restrict__ Bw,
                            float* __restrict__ C) {
    __shared__ float As[16 * 64];
    __shared__ float Bs[16 * 64];
    const int t = threadIdx.x;
    const size_t m0 = (size_t)blockIdx.x * 64;
    const int n0 = blockIdx.y * 64;
    const int tn = t & 15, tm = t >> 4;      // 16x16 thread grid, 4x4 microtile
    const int lm = t >> 2, lk = (t & 3) << 2;
    const float* Ap = A + (m0 + (size_t)lm) * IN_F + lk;
    const float* Bp = Bw + (size_t)(n0 + lm) * IN_F + lk;
    float acc[4][4] = {{0.f}};
    for (int k0 = 0; k0 < IN_F; k0 += 16) {
        float4 a4 = *(const float4*)(Ap + k0);
        float4 b4 = *(const float4*)(Bp + k0);
        __syncthreads();
        As[(lk + 0) * 64 + lm] = a4.x;
        As[(lk + 1) * 64 + lm] = a4.y;
        As[(lk + 2) * 64 + lm] = a4.z;
        As[(lk + 3) * 64 + lm] = a4.w;
        Bs[(lk + 0) * 64 + lm] = b4.x;
        Bs[(lk + 1) * 64 + lm] = b4.y;
        Bs[(lk + 2) * 64 + lm] = b4.z;
        Bs[(lk + 3) * 64 + lm] = b4.w;
        __syncthreads();
        #pragma unroll
        for (int k = 0; k < 16; ++k) {
            float4 av = *(const float4*)&As[k * 64 + 4 * tm];
            float4 bv = *(const float4*)&Bs[k * 64 + 4 * tn];
            acc[0][0] += av.x * bv.x; acc[0][1] += av.x * bv.y; acc[0][2] += av.x * bv.z; acc[0][3] += av.x * bv.w;
            acc[1][0] += av.y * bv.x; acc[1][1] += av.y * bv.y; acc[1][2] += av.y * bv.z; acc[1][3] += av.y * bv.w;
            acc[2][0] += av.z * bv.x; acc[2][1] += av.z * bv.y; acc[2][2] += av.z * bv.z; acc[2][3] += av.z * bv.w;
            acc[3][0] += av.w * bv.x; acc[3][1] += av.w * bv.y; acc[3][2] += av.w * bv.z; acc[3][3] += av.w * bv.w;
        }
    }
    float* Cp = C + (m0 + (size_t)(4 * tm)) * HID + n0 + 4 * tn;
    #pragma unroll
    for (int r = 0; r < 4; ++r) {
        float4 cv = make_float4(acc[r][0], acc[r][1], acc[r][2], acc[r][3]);
        *(float4*)(Cp + (size_t)r * HID) = cv;
    }
}

// ===== R1's proven 3-barrier rec kernel, slimmed: no LDS wout staging =====
// One block per batch element; 512 threads (thread = hidden unit h).
// LDS ~4.4 KB -> 4 blocks/CU resident (1024 blocks = exactly 4/CU).
// Closed-loop arithmetic bit-identical to R1's passing run.
__launch_bounds__(512, 8)
__global__ void rec_kernel(const float* __restrict__ cur,
                           const float* __restrict__ wrecT,
                           const float* __restrict__ woutT,
                           float* __restrict__ stV, float* __restrict__ stI,
                           float* __restrict__ stVO, float* __restrict__ stIO,
                           unsigned long long* __restrict__ stZM,
                           float* __restrict__ out, int t0, int csteps) {
    __shared__ __attribute__((aligned(16))) unsigned short slist[2][528];
    __shared__ unsigned long long zm[8];
    __shared__ float ypart[8][64];

    const int b = blockIdx.x;
    const int tid = threadIdx.x;
    const int lane = tid & 63;
    const int w = tid >> 6;

    float v  = stV[b * HID + tid];
    float ii = stI[b * HID + tid];
    float vo = 0.f, io = 0.f;
    if (tid < OUT_F) { vo = stVO[b * OUT_F + tid]; io = stIO[b * OUT_F + tid]; }
    if (tid < 8) zm[tid] = stZM[b * 8 + tid];
    __syncthreads();

    int cnt, cpad;
    {   // initial spike list (buffer 0) from persisted masks
        unsigned long long mm[8];
        #pragma unroll
        for (int q = 0; q < 8; ++q) mm[q] = zm[q];
        int pre = 0, total = 0;
        #pragma unroll
        for (int q = 0; q < 8; ++q) { int pc = (int)__popcll(mm[q]); total += pc; if (q < w) pre += pc; }
        int below = (int)__popcll(mm[w] & ((1ull << lane) - 1ull));
        if ((mm[w] >> lane) & 1ull) slist[0][pre + below] = (unsigned short)tid;
        cnt = total; cpad = (cnt + 7) & ~7;
        if (tid < 8 && cnt + tid < cpad) slist[0][cnt + tid] = (unsigned short)HID;
    }
    __syncthreads();

    float curv = cur[(size_t)b * HID + tid];   // step 0
    int cb = 0;
    for (int tl = 0; tl < csteps; ++tl) {
        float cur_nxt = 0.f;
        if (tl + 1 < csteps)
            cur_nxt = cur[((size_t)(tl + 1) * BATCH + b) * HID + tid];   // prefetch

        // recurrent input from z_{t-1} (ascending spike order; pad rows zero)
        float rec = 0.f;
        for (int k = 0; k < cpad; k += 8) {
            uint4 pk = *(const uint4*)&slist[cb][k];
            int j0 = pk.x & 0xffff, j1 = pk.x >> 16;
            int j2 = pk.y & 0xffff, j3 = pk.y >> 16;
            int j4 = pk.z & 0xffff, j5 = pk.z >> 16;
            int j6 = pk.w & 0xffff, j7 = pk.w >> 16;
            rec += wrecT[j0 * HID + tid];
            rec += wrecT[j1 * HID + tid];
            rec += wrecT[j2 * HID + tid];
            rec += wrecT[j3 * HID + tid];
            rec += wrecT[j4 * HID + tid];
            rec += wrecT[j5 * HID + tid];
            rec += wrecT[j6 * HID + tid];
            rec += wrecT[j7 * HID + tid];
        }
        // LIF update (expression forms mirror the reference)
        float vdec = v + 0.1f * ((0.0f - v) + ii);
        int spike = (vdec > 1.0f) ? 1 : 0;
        v = spike ? 0.0f : vdec;
        float idec = ii + 0.2f * (0.0f - ii);
        ii = (idec + curv) + rec;
        curv = cur_nxt;

        unsigned long long m = __ballot(spike);
        if (lane == 0) zm[w] = m;
        __syncthreads();                                   // (1) masks visible
        {   // build new spike list into slist[cb^1]
            unsigned long long mq[8];
            #pragma unroll
            for (int q = 0; q < 8; ++q) mq[q] = zm[q];
            int pre = 0, total = 0;
            #pragma unroll
            for (int q = 0; q < 8; ++q) { int pc = (int)__popcll(mq[q]); total += pc; if (q < w) pre += pc; }
            int below = (int)__popcll(mq[w] & ((1ull << lane) - 1ull));
            if ((mq[w] >> lane) & 1ull) slist[cb ^ 1][pre + below] = (unsigned short)tid;
            cnt = total; cpad = (cnt + 7) & ~7;
            if (tid < 8 && cnt + tid < cpad) slist[cb ^ 1][cnt + tid] = (unsigned short)HID;
        }
        __syncthreads();                                   // (2) list visible
        {   // readout y = z_new @ w_out^T (fp32 from L2), split across 8 waves
            float yp = 0.f;
            for (int k = w; k < cnt; k += 8) {
                int hh = slist[cb ^ 1][k];
                yp += woutT[hh * OUT_F + lane];
            }
            ypart[w][lane] = yp;
        }
        __syncthreads();                                   // (3) partials visible
        if (tid < OUT_F) {
            float y = 0.f;
            #pragma unroll
            for (int q = 0; q < 8; ++q) y += ypart[q][tid];
            float von = vo + 0.1f * ((0.0f - vo) + io);
            float iodec = io + 0.2f * (0.0f - io);
            io = iodec + y;
            vo = von;
            out[(((size_t)(t0 + tl)) * BATCH + b) * OUT_F + tid] = von;
        }
        cb ^= 1;
    }
    stV[b * HID + tid] = v;
    stI[b * HID + tid] = ii;
    if (tid < OUT_F) { stVO[b * OUT_F + tid] = vo; stIO[b * OUT_F + tid] = io; }
    if (tid < 8) stZM[b * 8 + tid] = zm[tid];
}

extern "C" void kernel_launch(void* const* d_in, const int* in_sizes, int n_in,
                              void* d_out, int out_size, void* d_ws, size_t ws_size,
                              hipStream_t stream) {
    const float* x     = (const float*)d_in[0];
    const float* w_in  = (const float*)d_in[1];
    const float* w_rec = (const float*)d_in[2];
    const float* w_out = (const float*)d_in[3];
    float* out = (float*)d_out;
    char* ws = (char*)d_ws;

    float* stV  = (float*)(ws + OFF_V);
    float* stI  = (float*)(ws + OFF_I);
    float* stVO = (float*)(ws + OFF_VO);
    float* stIO = (float*)(ws + OFF_IO);
    unsigned long long* stZM = (unsigned long long*)(ws + OFF_ZM);
    float* wrecT = (float*)(ws + OFF_WRT);
    float* woutT = (float*)(ws + OFF_WOT);
    float* curbuf = (float*)(ws + OFF_CUR);

    // largest power-of-2 step chunk whose cur buffer fits the scratch
    size_t cap = (ws_size > OFF_CUR) ? (ws_size - OFF_CUR) : 0;
    int csteps = 1;
    for (int c = 512; c >= 1; c >>= 1) {
        if ((size_t)c * (size_t)BATCH * HID * 4 <= cap) { csteps = c; break; }
    }

    {   // zero persistent state (v, i, vo, io, zmask)
        int n4 = (int)(OFF_WRT / 16);
        int blocks = (n4 + 255) / 256;
        if (blocks > 4096) blocks = 4096;
        hipLaunchKernelGGL(init_state_kernel, dim3(blocks), dim3(256), 0, stream,
                           (float4*)ws, n4);
    }
    hipLaunchKernelGGL(prep_kernel, dim3(512), dim3(256), 0, stream,
                       w_rec, w_out, wrecT, woutT);

    for (int t0 = 0; t0 < SEQ; t0 += csteps) {
        hipLaunchKernelGGL(gemm_kernel, dim3(csteps * (BATCH / 64), HID / 64), dim3(256), 0, stream,
                           x + (size_t)t0 * BATCH * IN_F, w_in, curbuf);
        hipLaunchKernelGGL(rec_kernel, dim3(BATCH), dim3(512), 0, stream,
                           curbuf, wrecT, woutT, stV, stI, stVO, stIO, stZM, out, t0, csteps);
    }
}

// Round 6
// 3657.236 us; speedup vs baseline: 1.2118x; 1.0240x over previous
//
#include <hip/hip_runtime.h>
#include <hip/hip_bf16.h>
#include <stdint.h>

#define SEQ   512
#define BATCH 1024
#define IN_F  256
#define HID   512
#define OUT_F 64

// ws layout (bytes)
static const size_t OFF_V   = 0;          // 1024*512*4 = 2 MB
static const size_t OFF_I   = 2097152;    // 2 MB
static const size_t OFF_VO  = 4194304;    // 256 KB
static const size_t OFF_IO  = 4456448;    // 256 KB
static const size_t OFF_ZM  = 4718592;    // 64 KB
static const size_t OFF_WRT = 4784128;    // 513*512*4 (row 512 zeros)
static const size_t OFF_WOT = 5834752;    // 513*64*4 = 131328 (fp32, row 512 zeros)
static const size_t OFF_CUR = 5966080;    // csteps*1024*512*4

__global__ void init_state_kernel(float4* __restrict__ p, int n4) {
    int i = blockIdx.x * blockDim.x + threadIdx.x;
    int stride = gridDim.x * blockDim.x;
    float4 z = make_float4(0.f, 0.f, 0.f, 0.f);
    for (; i < n4; i += stride) p[i] = z;
}

__global__ void prep_kernel(const float* __restrict__ wrec, const float* __restrict__ wout,
                            float* __restrict__ wrecT, float* __restrict__ woutT) {
    int i = blockIdx.x * blockDim.x + threadIdx.x;
    int stride = gridDim.x * blockDim.x;
    for (int idx = i; idx < 513 * 512; idx += stride) {
        int j = idx >> 9, h = idx & 511;
        wrecT[idx] = (j < 512) ? wrec[h * 512 + j] : 0.0f;   // wrecT[j][h] = w_rec[h][j]
    }
    for (int idx = i; idx < 513 * 64; idx += stride) {
        int h = idx >> 6, o = idx & 63;
        woutT[idx] = (h < 512) ? wout[o * 512 + h] : 0.0f;   // woutT[h][o] = w_out[o][h]
    }
}

// ===== VERBATIM R1/R3 GEMM (fp32 VALU) — numerics LOCKED (bit-exact cur) =====
// Sequential-k fused fmac chain per output element == BLAS microkernel order.
// At 101 TF ≈ 98% of the measured VALU ceiling (103 TF). Do NOT change.
__launch_bounds__(256)
__global__ void gemm_kernel(const float* __restrict__ A, const float* __restrict__ Bw,
                            float* __restrict__ C) {
    __shared__ float As[16 * 64];
    __shared__ float Bs[16 * 64];
    const int t = threadIdx.x;
    const size_t m0 = (size_t)blockIdx.x * 64;
    const int n0 = blockIdx.y * 64;
    const int tn = t & 15, tm = t >> 4;      // 16x16 thread grid, 4x4 microtile
    const int lm = t >> 2, lk = (t & 3) << 2;
    const float* Ap = A + (m0 + (size_t)lm) * IN_F + lk;
    const float* Bp = Bw + (size_t)(n0 + lm) * IN_F + lk;
    float acc[4][4] = {{0.f}};
    for (int k0 = 0; k0 < IN_F; k0 += 16) {
        float4 a4 = *(const float4*)(Ap + k0);
        float4 b4 = *(const float4*)(Bp + k0);
        __syncthreads();
        As[(lk + 0) * 64 + lm] = a4.x;
        As[(lk + 1) * 64 + lm] = a4.y;
        As[(lk + 2) * 64 + lm] = a4.z;
        As[(lk + 3) * 64 + lm] = a4.w;
        Bs[(lk + 0) * 64 + lm] = b4.x;
        Bs[(lk + 1) * 64 + lm] = b4.y;
        Bs[(lk + 2) * 64 + lm] = b4.z;
        Bs[(lk + 3) * 64 + lm] = b4.w;
        __syncthreads();
        #pragma unroll
        for (int k = 0; k < 16; ++k) {
            float4 av = *(const float4*)&As[k * 64 + 4 * tm];
            float4 bv = *(const float4*)&Bs[k * 64 + 4 * tn];
            acc[0][0] += av.x * bv.x; acc[0][1] += av.x * bv.y; acc[0][2] += av.x * bv.z; acc[0][3] += av.x * bv.w;
            acc[1][0] += av.y * bv.x; acc[1][1] += av.y * bv.y; acc[1][2] += av.y * bv.z; acc[1][3] += av.y * bv.w;
            acc[2][0] += av.z * bv.x; acc[2][1] += av.z * bv.y; acc[2][2] += av.z * bv.z; acc[2][3] += av.z * bv.w;
            acc[3][0] += av.w * bv.x; acc[3][1] += av.w * bv.y; acc[3][2] += av.w * bv.z; acc[3][3] += av.w * bv.w;
        }
    }
    float* Cp = C + (m0 + (size_t)(4 * tm)) * HID + n0 + 4 * tn;
    #pragma unroll
    for (int r = 0; r < 4; ++r) {
        float4 cv = make_float4(acc[r][0], acc[r][1], acc[r][2], acc[r][3]);
        *(float4*)(Cp + (size_t)r * HID) = cv;
    }
}

// ===== rec kernel: R5 structure, 32-bit OR-fused gather addressing =====
// One block per batch element; 512 threads (thread = hidden unit h).
// Gather offsets: (j << 11) | (tid << 2) — disjoint bits, one v_lshl_or_b32
// per load against an SGPR-resident base. Arithmetic order bit-identical to R5.
__launch_bounds__(512, 8)
__global__ void rec_kernel(const float* __restrict__ cur,
                           const float* __restrict__ wrecT,
                           const float* __restrict__ woutT,
                           float* __restrict__ stV, float* __restrict__ stI,
                           float* __restrict__ stVO, float* __restrict__ stIO,
                           unsigned long long* __restrict__ stZM,
                           float* __restrict__ out, int t0, int csteps) {
    __shared__ __attribute__((aligned(16))) unsigned short slist[2][528];
    __shared__ unsigned long long zm[8];
    __shared__ float ypart[8][64];

    const int b = blockIdx.x;
    const int tid = threadIdx.x;
    const int lane = tid & 63;
    const int w = tid >> 6;
    const int t4 = tid << 2;          // voffset within a wrecT row
    const int l4 = lane << 2;         // voffset within a woutT row

    const char* __restrict__ wrecB = (const char*)wrecT;
    const char* __restrict__ woutB = (const char*)woutT;

    float v  = stV[b * HID + tid];
    float ii = stI[b * HID + tid];
    float vo = 0.f, io = 0.f;
    if (tid < OUT_F) { vo = stVO[b * OUT_F + tid]; io = stIO[b * OUT_F + tid]; }
    if (tid < 8) zm[tid] = stZM[b * 8 + tid];
    __syncthreads();

    int cnt, cpad;
    {   // initial spike list (buffer 0) from persisted masks
        unsigned long long mm[8];
        #pragma unroll
        for (int q = 0; q < 8; ++q) mm[q] = zm[q];
        int pre = 0, total = 0;
        #pragma unroll
        for (int q = 0; q < 8; ++q) { int pc = (int)__popcll(mm[q]); total += pc; if (q < w) pre += pc; }
        int below = (int)__popcll(mm[w] & ((1ull << lane) - 1ull));
        if ((mm[w] >> lane) & 1ull) slist[0][pre + below] = (unsigned short)tid;
        cnt = total; cpad = (cnt + 7) & ~7;
        if (tid < 8 && cnt + tid < cpad) slist[0][cnt + tid] = (unsigned short)HID;
    }
    __syncthreads();

    // walking row pointer: SGPR base + tid*4 voffset
    const float* __restrict__ curRow  = cur + (size_t)b * HID;
    const size_t step_stride = (size_t)BATCH * HID;

    float curv = curRow[tid];   // step 0
    int cb = 0;
    for (int tl = 0; tl < csteps; ++tl) {
        float cur_nxt = 0.f;
        if (tl + 1 < csteps) {
            curRow += step_stride;
            cur_nxt = curRow[tid];                          // prefetch next step
        }

        // recurrent input from z_{t-1} (ascending spike order; pad rows zero)
        float rec = 0.f;
        for (int k = 0; k < cpad; k += 8) {
            uint4 pk = *(const uint4*)&slist[cb][k];
            int o0 = ((pk.x & 0xffff) << 11) | t4;
            int o1 = ((pk.x >> 16) << 11) | t4;
            int o2 = ((pk.y & 0xffff) << 11) | t4;
            int o3 = ((pk.y >> 16) << 11) | t4;
            int o4 = ((pk.z & 0xffff) << 11) | t4;
            int o5 = ((pk.z >> 16) << 11) | t4;
            int o6 = ((pk.w & 0xffff) << 11) | t4;
            int o7 = ((pk.w >> 16) << 11) | t4;
            rec += *(const float*)(wrecB + o0);
            rec += *(const float*)(wrecB + o1);
            rec += *(const float*)(wrecB + o2);
            rec += *(const float*)(wrecB + o3);
            rec += *(const float*)(wrecB + o4);
            rec += *(const float*)(wrecB + o5);
            rec += *(const float*)(wrecB + o6);
            rec += *(const float*)(wrecB + o7);
        }
        // LIF update (expression forms mirror the reference)
        float vdec = v + 0.1f * ((0.0f - v) + ii);
        int spike = (vdec > 1.0f) ? 1 : 0;
        v = spike ? 0.0f : vdec;
        float idec = ii + 0.2f * (0.0f - ii);
        ii = (idec + curv) + rec;
        curv = cur_nxt;

        unsigned long long m = __ballot(spike);
        if (lane == 0) zm[w] = m;
        __syncthreads();                                   // (1) masks visible
        {   // build new spike list into slist[cb^1]
            unsigned long long mq[8];
            #pragma unroll
            for (int q = 0; q < 8; ++q) mq[q] = zm[q];
            int pre = 0, total = 0;
            #pragma unroll
            for (int q = 0; q < 8; ++q) { int pc = (int)__popcll(mq[q]); total += pc; if (q < w) pre += pc; }
            int below = (int)__popcll(mq[w] & ((1ull << lane) - 1ull));
            if ((mq[w] >> lane) & 1ull) slist[cb ^ 1][pre + below] = (unsigned short)tid;
            cnt = total; cpad = (cnt + 7) & ~7;
            if (tid < 8 && cnt + tid < cpad) slist[cb ^ 1][cnt + tid] = (unsigned short)HID;
        }
        __syncthreads();                                   // (2) list visible
        {   // readout y = z_new @ w_out^T (fp32 from L2), split across 8 waves
            float yp = 0.f;
            for (int k = w; k < cnt; k += 8) {
                int hh = slist[cb ^ 1][k];
                yp += *(const float*)(woutB + ((hh << 8) | l4));
            }
            ypart[w][lane] = yp;
        }
        __syncthreads();                                   // (3) partials visible
        if (tid < OUT_F) {
            float y = 0.f;
            #pragma unroll
            for (int q = 0; q < 8; ++q) y += ypart[q][tid];
            float von = vo + 0.1f * ((0.0f - vo) + io);
            float iodec = io + 0.2f * (0.0f - io);
            io = iodec + y;
            vo = von;
            out[(((size_t)(t0 + tl)) * BATCH + b) * OUT_F + tid] = von;
        }
        cb ^= 1;
    }
    stV[b * HID + tid] = v;
    stI[b * HID + tid] = ii;
    if (tid < OUT_F) { stVO[b * OUT_F + tid] = vo; stIO[b * OUT_F + tid] = io; }
    if (tid < 8) stZM[b * 8 + tid] = zm[tid];
}

extern "C" void kernel_launch(void* const* d_in, const int* in_sizes, int n_in,
                              void* d_out, int out_size, void* d_ws, size_t ws_size,
                              hipStream_t stream) {
    const float* x     = (const float*)d_in[0];
    const float* w_in  = (const float*)d_in[1];
    const float* w_rec = (const float*)d_in[2];
    const float* w_out = (const float*)d_in[3];
    float* out = (float*)d_out;
    char* ws = (char*)d_ws;

    float* stV  = (float*)(ws + OFF_V);
    float* stI  = (float*)(ws + OFF_I);
    float* stVO = (float*)(ws + OFF_VO);
    float* stIO = (float*)(ws + OFF_IO);
    unsigned long long* stZM = (unsigned long long*)(ws + OFF_ZM);
    float* wrecT = (float*)(ws + OFF_WRT);
    float* woutT = (float*)(ws + OFF_WOT);
    float* curbuf = (float*)(ws + OFF_CUR);

    // largest power-of-2 step chunk whose cur buffer fits the scratch
    size_t cap = (ws_size > OFF_CUR) ? (ws_size - OFF_CUR) : 0;
    int csteps = 1;
    for (int c = 512; c >= 1; c >>= 1) {
        if ((size_t)c * (size_t)BATCH * HID * 4 <= cap) { csteps = c; break; }
    }

    {   // zero persistent state (v, i, vo, io, zmask)
        int n4 = (int)(OFF_WRT / 16);
        int blocks = (n4 + 255) / 256;
        if (blocks > 4096) blocks = 4096;
        hipLaunchKernelGGL(init_state_kernel, dim3(blocks), dim3(256), 0, stream,
                           (float4*)ws, n4);
    }
    hipLaunchKernelGGL(prep_kernel, dim3(512), dim3(256), 0, stream,
                       w_rec, w_out, wrecT, woutT);

    for (int t0 = 0; t0 < SEQ; t0 += csteps) {
        hipLaunchKernelGGL(gemm_kernel, dim3(csteps * (BATCH / 64), HID / 64), dim3(256), 0, stream,
                           x + (size_t)t0 * BATCH * IN_F, w_in, curbuf);
        hipLaunchKernelGGL(rec_kernel, dim3(BATCH), dim3(512), 0, stream,
                           curbuf, wrecT, woutT, stV, stI, stVO, stIO, stZM, out, t0, csteps);
    }
}

// Round 7
// 2996.872 us; speedup vs baseline: 1.4788x; 1.2204x over previous
//
#include <hip/hip_runtime.h>
#include <hip/hip_bf16.h>
#include <stdint.h>

#define SEQ   512
#define BATCH 1024
#define IN_F  256
#define HID   512
#define OUT_F 64

typedef float f32x2 __attribute__((ext_vector_type(2)));

// ws layout (bytes)
static const size_t OFF_V   = 0;          // 1024*512*4 = 2 MB
static const size_t OFF_I   = 2097152;    // 2 MB
static const size_t OFF_VO  = 4194304;    // 256 KB
static const size_t OFF_IO  = 4456448;    // 256 KB
static const size_t OFF_ZM  = 4718592;    // 64 KB
static const size_t OFF_WRT = 4784128;    // 513*512*4 (row 512 zeros)
static const size_t OFF_WOT = 5834752;    // 513*64*4 = 131328 (fp32, row 512 zeros)
static const size_t OFF_CUR = 5966080;    // csteps*1024*512*4

__global__ void init_state_kernel(float4* __restrict__ p, int n4) {
    int i = blockIdx.x * blockDim.x + threadIdx.x;
    int stride = gridDim.x * blockDim.x;
    float4 z = make_float4(0.f, 0.f, 0.f, 0.f);
    for (; i < n4; i += stride) p[i] = z;
}

__global__ void prep_kernel(const float* __restrict__ wrec, const float* __restrict__ wout,
                            float* __restrict__ wrecT, float* __restrict__ woutT) {
    int i = blockIdx.x * blockDim.x + threadIdx.x;
    int stride = gridDim.x * blockDim.x;
    for (int idx = i; idx < 513 * 512; idx += stride) {
        int j = idx >> 9, h = idx & 511;
        wrecT[idx] = (j < 512) ? wrec[h * 512 + j] : 0.0f;   // wrecT[j][h] = w_rec[h][j]
    }
    for (int idx = i; idx < 513 * 64; idx += stride) {
        int h = idx >> 6, o = idx & 63;
        woutT[idx] = (h < 512) ? wout[o * 512 + h] : 0.0f;   // woutT[h][o] = w_out[o][h]
    }
}

// ===== fp32 VALU GEMM, restructured. NUMERICS LOCKED: each C[m][n] is ONE
// fma chain over k = 0..255 ascending (bit-identical to R3/R5/R6's passing
// kernels and to np's OpenBLAS microkernel). Structural changes only:
// 128x128 tile, BK=32, 8x8 microtile, k-major LDS (2-way-free banking),
// f32x2 packed fma, XCD-chunked swizzle (n-inner) for A-panel L2 reuse. =====
#define GBM 128
#define GBN 128
#define GBK 32
#define GLDK 132   // padded row stride (floats); 132%4==0 keeps float4 align

__launch_bounds__(256)
__global__ void gemm_kernel(const float* __restrict__ A, const float* __restrict__ Bw,
                            float* __restrict__ C) {
    __shared__ float As[GBK][GLDK];   // [k][m]
    __shared__ float Bs[GBK][GLDK];   // [k][n]

    // XCD-chunked swizzle (bijective: gridDim.x % 8 == 0). n-inner: the 4
    // n-tiles of one m-tile are consecutive logicals -> same XCD chunk.
    const int nwg = gridDim.x;
    const int cpx = nwg >> 3;
    const int logical = ((int)blockIdx.x & 7) * cpx + ((int)blockIdx.x >> 3);
    const int mb = logical >> 2;
    const int nb = logical & 3;

    const int t = threadIdx.x;
    const size_t m0 = (size_t)mb * GBM;
    const int n0 = nb * GBN;

    // staging: thread t covers row r = t>>1, k-half = (t&1)*16 (16 floats)
    const int r  = t >> 1;
    const int kh = (t & 1) << 4;
    const float* Ap = A  + (m0 + (size_t)r) * IN_F + kh;
    const float* Bp = Bw + (size_t)(n0 + r) * IN_F + kh;

    // microtile: thread (tm, tn) owns rows tm*8.., cols tn*8..
    const int tm = t >> 4;
    const int tn = t & 15;

    f32x2 acc[8][4] = {};

    for (int k0 = 0; k0 < IN_F; k0 += GBK) {
        float4 a0 = *(const float4*)(Ap + k0);
        float4 a1 = *(const float4*)(Ap + k0 + 4);
        float4 a2 = *(const float4*)(Ap + k0 + 8);
        float4 a3 = *(const float4*)(Ap + k0 + 12);
        float4 b0 = *(const float4*)(Bp + k0);
        float4 b1 = *(const float4*)(Bp + k0 + 4);
        float4 b2 = *(const float4*)(Bp + k0 + 8);
        float4 b3 = *(const float4*)(Bp + k0 + 12);
        __syncthreads();   // previous iteration's readers done
        {
            float av[16], bv[16];
            *(float4*)(av + 0) = a0; *(float4*)(av + 4)  = a1;
            *(float4*)(av + 8) = a2; *(float4*)(av + 12) = a3;
            *(float4*)(bv + 0) = b0; *(float4*)(bv + 4)  = b1;
            *(float4*)(bv + 8) = b2; *(float4*)(bv + 12) = b3;
            #pragma unroll
            for (int i = 0; i < 16; ++i) {
                As[kh + i][r] = av[i];   // bank (4(kh+i)+r)%32: 2-way, free
                Bs[kh + i][r] = bv[i];
            }
        }
        __syncthreads();
        #pragma unroll
        for (int k = 0; k < GBK; ++k) {
            float am[8], bn[8];
            *(float4*)(am + 0) = *(const float4*)&As[k][tm * 8];
            *(float4*)(am + 4) = *(const float4*)&As[k][tm * 8 + 4];
            *(float4*)(bn + 0) = *(const float4*)&Bs[k][tn * 8];
            *(float4*)(bn + 4) = *(const float4*)&Bs[k][tn * 8 + 4];
            f32x2 bp0 = { bn[0], bn[1] }, bp1 = { bn[2], bn[3] };
            f32x2 bp2 = { bn[4], bn[5] }, bp3 = { bn[6], bn[7] };
            #pragma unroll
            for (int rr = 0; rr < 8; ++rr) {
                f32x2 ar = { am[rr], am[rr] };
                acc[rr][0] = __builtin_elementwise_fma(ar, bp0, acc[rr][0]);
                acc[rr][1] = __builtin_elementwise_fma(ar, bp1, acc[rr][1]);
                acc[rr][2] = __builtin_elementwise_fma(ar, bp2, acc[rr][2]);
                acc[rr][3] = __builtin_elementwise_fma(ar, bp3, acc[rr][3]);
            }
        }
    }
    // epilogue: two float4 stores per microtile row
    #pragma unroll
    for (int rr = 0; rr < 8; ++rr) {
        float* Cp = C + (m0 + (size_t)(tm * 8 + rr)) * HID + n0 + tn * 8;
        float4 c0 = make_float4(acc[rr][0][0], acc[rr][0][1], acc[rr][1][0], acc[rr][1][1]);
        float4 c1 = make_float4(acc[rr][2][0], acc[rr][2][1], acc[rr][3][0], acc[rr][3][1]);
        *(float4*)(Cp + 0) = c0;
        *(float4*)(Cp + 4) = c1;
    }
}

// ===== rec kernel: VERBATIM R6 (passed, 2.1 ms ≈ 87% of L2 roofline) =====
__launch_bounds__(512, 8)
__global__ void rec_kernel(const float* __restrict__ cur,
                           const float* __restrict__ wrecT,
                           const float* __restrict__ woutT,
                           float* __restrict__ stV, float* __restrict__ stI,
                           float* __restrict__ stVO, float* __restrict__ stIO,
                           unsigned long long* __restrict__ stZM,
                           float* __restrict__ out, int t0, int csteps) {
    __shared__ __attribute__((aligned(16))) unsigned short slist[2][528];
    __shared__ unsigned long long zm[8];
    __shared__ float ypart[8][64];

    const int b = blockIdx.x;
    const int tid = threadIdx.x;
    const int lane = tid & 63;
    const int w = tid >> 6;
    const int t4 = tid << 2;          // voffset within a wrecT row
    const int l4 = lane << 2;         // voffset within a woutT row

    const char* __restrict__ wrecB = (const char*)wrecT;
    const char* __restrict__ woutB = (const char*)woutT;

    float v  = stV[b * HID + tid];
    float ii = stI[b * HID + tid];
    float vo = 0.f, io = 0.f;
    if (tid < OUT_F) { vo = stVO[b * OUT_F + tid]; io = stIO[b * OUT_F + tid]; }
    if (tid < 8) zm[tid] = stZM[b * 8 + tid];
    __syncthreads();

    int cnt, cpad;
    {   // initial spike list (buffer 0) from persisted masks
        unsigned long long mm[8];
        #pragma unroll
        for (int q = 0; q < 8; ++q) mm[q] = zm[q];
        int pre = 0, total = 0;
        #pragma unroll
        for (int q = 0; q < 8; ++q) { int pc = (int)__popcll(mm[q]); total += pc; if (q < w) pre += pc; }
        int below = (int)__popcll(mm[w] & ((1ull << lane) - 1ull));
        if ((mm[w] >> lane) & 1ull) slist[0][pre + below] = (unsigned short)tid;
        cnt = total; cpad = (cnt + 7) & ~7;
        if (tid < 8 && cnt + tid < cpad) slist[0][cnt + tid] = (unsigned short)HID;
    }
    __syncthreads();

    // walking row pointer: SGPR base + tid*4 voffset
    const float* __restrict__ curRow  = cur + (size_t)b * HID;
    const size_t step_stride = (size_t)BATCH * HID;

    float curv = curRow[tid];   // step 0
    int cb = 0;
    for (int tl = 0; tl < csteps; ++tl) {
        float cur_nxt = 0.f;
        if (tl + 1 < csteps) {
            curRow += step_stride;
            cur_nxt = curRow[tid];                          // prefetch next step
        }

        // recurrent input from z_{t-1} (ascending spike order; pad rows zero)
        float rec = 0.f;
        for (int k = 0; k < cpad; k += 8) {
            uint4 pk = *(const uint4*)&slist[cb][k];
            int o0 = ((pk.x & 0xffff) << 11) | t4;
            int o1 = ((pk.x >> 16) << 11) | t4;
            int o2 = ((pk.y & 0xffff) << 11) | t4;
            int o3 = ((pk.y >> 16) << 11) | t4;
            int o4 = ((pk.z & 0xffff) << 11) | t4;
            int o5 = ((pk.z >> 16) << 11) | t4;
            int o6 = ((pk.w & 0xffff) << 11) | t4;
            int o7 = ((pk.w >> 16) << 11) | t4;
            rec += *(const float*)(wrecB + o0);
            rec += *(const float*)(wrecB + o1);
            rec += *(const float*)(wrecB + o2);
            rec += *(const float*)(wrecB + o3);
            rec += *(const float*)(wrecB + o4);
            rec += *(const float*)(wrecB + o5);
            rec += *(const float*)(wrecB + o6);
            rec += *(const float*)(wrecB + o7);
        }
        // LIF update (expression forms mirror the reference)
        float vdec = v + 0.1f * ((0.0f - v) + ii);
        int spike = (vdec > 1.0f) ? 1 : 0;
        v = spike ? 0.0f : vdec;
        float idec = ii + 0.2f * (0.0f - ii);
        ii = (idec + curv) + rec;
        curv = cur_nxt;

        unsigned long long m = __ballot(spike);
        if (lane == 0) zm[w] = m;
        __syncthreads();                                   // (1) masks visible
        {   // build new spike list into slist[cb^1]
            unsigned long long mq[8];
            #pragma unroll
            for (int q = 0; q < 8; ++q) mq[q] = zm[q];
            int pre = 0, total = 0;
            #pragma unroll
            for (int q = 0; q < 8; ++q) { int pc = (int)__popcll(mq[q]); total += pc; if (q < w) pre += pc; }
            int below = (int)__popcll(mq[w] & ((1ull << lane) - 1ull));
            if ((mq[w] >> lane) & 1ull) slist[cb ^ 1][pre + below] = (unsigned short)tid;
            cnt = total; cpad = (cnt + 7) & ~7;
            if (tid < 8 && cnt + tid < cpad) slist[cb ^ 1][cnt + tid] = (unsigned short)HID;
        }
        __syncthreads();                                   // (2) list visible
        {   // readout y = z_new @ w_out^T (fp32 from L2), split across 8 waves
            float yp = 0.f;
            for (int k = w; k < cnt; k += 8) {
                int hh = slist[cb ^ 1][k];
                yp += *(const float*)(woutB + ((hh << 8) | l4));
            }
            ypart[w][lane] = yp;
        }
        __syncthreads();                                   // (3) partials visible
        if (tid < OUT_F) {
            float y = 0.f;
            #pragma unroll
            for (int q = 0; q < 8; ++q) y += ypart[q][tid];
            float von = vo + 0.1f * ((0.0f - vo) + io);
            float iodec = io + 0.2f * (0.0f - io);
            io = iodec + y;
            vo = von;
            out[(((size_t)(t0 + tl)) * BATCH + b) * OUT_F + tid] = von;
        }
        cb ^= 1;
    }
    stV[b * HID + tid] = v;
    stI[b * HID + tid] = ii;
    if (tid < OUT_F) { stVO[b * OUT_F + tid] = vo; stIO[b * OUT_F + tid] = io; }
    if (tid < 8) stZM[b * 8 + tid] = zm[tid];
}

extern "C" void kernel_launch(void* const* d_in, const int* in_sizes, int n_in,
                              void* d_out, int out_size, void* d_ws, size_t ws_size,
                              hipStream_t stream) {
    const float* x     = (const float*)d_in[0];
    const float* w_in  = (const float*)d_in[1];
    const float* w_rec = (const float*)d_in[2];
    const float* w_out = (const float*)d_in[3];
    float* out = (float*)d_out;
    char* ws = (char*)d_ws;

    float* stV  = (float*)(ws + OFF_V);
    float* stI  = (float*)(ws + OFF_I);
    float* stVO = (float*)(ws + OFF_VO);
    float* stIO = (float*)(ws + OFF_IO);
    unsigned long long* stZM = (unsigned long long*)(ws + OFF_ZM);
    float* wrecT = (float*)(ws + OFF_WRT);
    float* woutT = (float*)(ws + OFF_WOT);
    float* curbuf = (float*)(ws + OFF_CUR);

    // largest power-of-2 step chunk whose cur buffer fits the scratch
    size_t cap = (ws_size > OFF_CUR) ? (ws_size - OFF_CUR) : 0;
    int csteps = 1;
    for (int c = 512; c >= 1; c >>= 1) {
        if ((size_t)c * (size_t)BATCH * HID * 4 <= cap) { csteps = c; break; }
    }

    {   // zero persistent state (v, i, vo, io, zmask)
        int n4 = (int)(OFF_WRT / 16);
        int blocks = (n4 + 255) / 256;
        if (blocks > 4096) blocks = 4096;
        hipLaunchKernelGGL(init_state_kernel, dim3(blocks), dim3(256), 0, stream,
                           (float4*)ws, n4);
    }
    hipLaunchKernelGGL(prep_kernel, dim3(512), dim3(256), 0, stream,
                       w_rec, w_out, wrecT, woutT);

    for (int t0 = 0; t0 < SEQ; t0 += csteps) {
        // grid: (csteps*1024/128) m-tiles x 4 n-tiles, flat, swizzled in-kernel
        hipLaunchKernelGGL(gemm_kernel, dim3(csteps * 32), dim3(256), 0, stream,
                           x + (size_t)t0 * BATCH * IN_F, w_in, curbuf);
        hipLaunchKernelGGL(rec_kernel, dim3(BATCH), dim3(512), 0, stream,
                           curbuf, wrecT, woutT, stV, stI, stVO, stIO, stZM, out, t0, csteps);
    }
}